// Round 1
// baseline (911.313 us; speedup 1.0000x reference)
//
#include <hip/hip_runtime.h>
#include <math.h>

#define N_NODES   50000
#define N_EDGES   800000
#define NUM_GRAPHS 64
#define FDIM      64
#define HDIM      64
#define NLAYERS   3
#define NCLASSES  16
#define EPS       1e-5f

#define SCAN_CHUNK 1024
#define NCHUNKS ((N_NODES + SCAN_CHUNK - 1) / SCAN_CHUNK)   // 49

// ---------------------------------------------------------------------------
// CSR build: degree histogram
__global__ void k_count(const int* __restrict__ dst, int* __restrict__ cnt) {
    int e = blockIdx.x * 256 + threadIdx.x;
    if (e < N_EDGES) atomicAdd(&cnt[dst[e]], 1);
}

// per-chunk sums (for scan) + sum of log(deg_raw+1) for avg_log
__global__ void k_chunk_sums(const int* __restrict__ cnt, int* __restrict__ bsum,
                             float* __restrict__ logsum) {
    __shared__ int   ired[256];
    __shared__ float lred[256];
    int b = blockIdx.x, t = threadIdx.x;
    int base = b * SCAN_CHUNK;
    int s = 0; float ls = 0.f;
    for (int i = t; i < SCAN_CHUNK; i += 256) {
        int idx = base + i;
        if (idx < N_NODES) {
            int v = cnt[idx];
            s += v;
            ls += logf((float)v + 1.0f);
        }
    }
    ired[t] = s; lred[t] = ls;
    __syncthreads();
    for (int off = 128; off > 0; off >>= 1) {
        if (t < off) { ired[t] += ired[t + off]; lred[t] += lred[t + off]; }
        __syncthreads();
    }
    if (t == 0) { bsum[b] = ired[0]; atomicAdd(logsum, lred[0]); }
}

__global__ void k_scan_top(const int* __restrict__ bsum, int* __restrict__ boff,
                           int* __restrict__ row_start) {
    if (threadIdx.x == 0) {
        int acc = 0;
        for (int i = 0; i < NCHUNKS; ++i) { boff[i] = acc; acc += bsum[i]; }
        row_start[N_NODES] = acc;
    }
}

__global__ void k_scan_chunks(const int* __restrict__ cnt, const int* __restrict__ boff,
                              int* __restrict__ row_start, int* __restrict__ cursor) {
    __shared__ int tsum[256];
    int b = blockIdx.x, t = threadIdx.x;
    int base = b * SCAN_CHUNK + t * 4;
    int v[4]; int s = 0;
    #pragma unroll
    for (int i = 0; i < 4; ++i) {
        int idx = base + i;
        v[i] = (idx < N_NODES) ? cnt[idx] : 0;
        s += v[i];
    }
    tsum[t] = s;
    __syncthreads();
    for (int off = 1; off < 256; off <<= 1) {
        int val = (t >= off) ? tsum[t - off] : 0;
        __syncthreads();
        tsum[t] += val;
        __syncthreads();
    }
    int excl = boff[b] + tsum[t] - s;   // exclusive prefix for first of my 4
    #pragma unroll
    for (int i = 0; i < 4; ++i) {
        int idx = base + i;
        if (idx < N_NODES) { row_start[idx] = excl; cursor[idx] = excl; }
        excl += v[i];
    }
}

__global__ void k_scatter(const int* __restrict__ src, const int* __restrict__ dst,
                          int* __restrict__ cursor, int* __restrict__ csr_src) {
    int e = blockIdx.x * 256 + threadIdx.x;
    if (e < N_EDGES) {
        int d = dst[e];
        int slot = atomicAdd(&cursor[d], 1);
        csr_src[slot] = src[e];
    }
}

// per-node degree scalers
__global__ void k_scal(const int* __restrict__ cnt, const float* __restrict__ logsum,
                       float* __restrict__ inv_deg, float* __restrict__ ampv,
                       float* __restrict__ attv) {
    int n = blockIdx.x * 256 + threadIdx.x;
    if (n < N_NODES) {
        float avg = logsum[0] / (float)N_NODES;
        float degf = fmaxf((float)cnt[n], 1.0f);
        inv_deg[n] = 1.0f / degf;
        float ld = logf(degf + 1.0f);
        ampv[n] = ld / avg;
        attv[n] = avg / ld;
    }
}

// ---------------------------------------------------------------------------
// p = x @ Wi^T + pre_b ; q = x @ Wj^T    (pre_w = [Wi | Wj], [64][128] row-major)
// 64 rows/block, 256 thr = 16x16 tile grid, each thread 4 rows x 4 cols.
__global__ __launch_bounds__(256) void k_pre(const float* __restrict__ x,
                                             const float* __restrict__ pre_w,
                                             const float* __restrict__ pre_b,
                                             float* __restrict__ p,
                                             float* __restrict__ q) {
    __shared__ float At[64][68];    // At[k][r] = x[rowBase+r][k]
    __shared__ float Wt[128][68];   // Wt[k][c] = pre_w[c][k]
    int t = threadIdx.x;
    int c4 = (t & 15) * 4;
    int r4 = (t >> 4) * 4;
    int rowBase = blockIdx.x * 64;

    for (int idx = t; idx < 64 * 128; idx += 256) {
        int cc = idx >> 7, k = idx & 127;
        Wt[k][cc] = pre_w[idx];
    }
    for (int idx = t; idx < 4096; idx += 256) {
        int r = idx >> 6, kk = idx & 63;
        int row = rowBase + r;
        At[kk][r] = (row < N_NODES) ? x[row * 64 + kk] : 0.f;
    }
    __syncthreads();

    float accp[4][4] = {{0}}, accq[4][4] = {{0}};
    #pragma unroll 4
    for (int kk = 0; kk < 64; ++kk) {
        float4 a  = *(const float4*)&At[kk][r4];
        float4 wp = *(const float4*)&Wt[kk][c4];
        float4 wq = *(const float4*)&Wt[64 + kk][c4];
        float av[4]  = {a.x, a.y, a.z, a.w};
        float wpv[4] = {wp.x, wp.y, wp.z, wp.w};
        float wqv[4] = {wq.x, wq.y, wq.z, wq.w};
        #pragma unroll
        for (int i = 0; i < 4; ++i)
            #pragma unroll
            for (int j = 0; j < 4; ++j) {
                accp[i][j] += av[i] * wpv[j];
                accq[i][j] += av[i] * wqv[j];
            }
    }
    float pb[4];
    #pragma unroll
    for (int j = 0; j < 4; ++j) pb[j] = pre_b[c4 + j];
    #pragma unroll
    for (int i = 0; i < 4; ++i) {
        int row = rowBase + r4 + i;
        if (row < N_NODES) {
            float4 vp = make_float4(accp[i][0] + pb[0], accp[i][1] + pb[1],
                                    accp[i][2] + pb[2], accp[i][3] + pb[3]);
            float4 vq = make_float4(accq[i][0], accq[i][1], accq[i][2], accq[i][3]);
            *(float4*)&p[row * 64 + c4] = vp;
            *(float4*)&q[row * 64 + c4] = vq;
        }
    }
}

// ---------------------------------------------------------------------------
// Aggregation: one wave per node, lane = channel. m_e = p[n] + q[src_e].
__global__ __launch_bounds__(256) void k_aggr(const float* __restrict__ p,
                                              const float* __restrict__ q,
                                              const int* __restrict__ row_start,
                                              const int* __restrict__ csr_src,
                                              const float* __restrict__ inv_deg,
                                              float* __restrict__ aggr) {
    int wid  = (blockIdx.x * 256 + threadIdx.x) >> 6;
    int lane = threadIdx.x & 63;
    if (wid >= N_NODES) return;
    int n = wid;
    float pv = p[n * 64 + lane];
    int beg = row_start[n], end = row_start[n + 1];
    float sum = 0.f, sq = 0.f;
    float mn = INFINITY, mx = -INFINITY;
    int e = beg;
    for (; e + 1 < end; e += 2) {
        int s0 = csr_src[e];
        int s1 = csr_src[e + 1];
        float m0 = pv + q[s0 * 64 + lane];
        float m1 = pv + q[s1 * 64 + lane];
        sum += m0; sq += m0 * m0; mn = fminf(mn, m0); mx = fmaxf(mx, m0);
        sum += m1; sq += m1 * m1; mn = fminf(mn, m1); mx = fmaxf(mx, m1);
    }
    if (e < end) {
        int s0 = csr_src[e];
        float m0 = pv + q[s0 * 64 + lane];
        sum += m0; sq += m0 * m0; mn = fminf(mn, m0); mx = fmaxf(mx, m0);
    }
    float id = inv_deg[n];
    float mean = sum * id;
    float var  = fmaxf(sq * id - mean * mean, 0.f);
    float sd   = sqrtf(var + EPS);
    if (end <= beg) { mn = 0.f; mx = 0.f; }
    float* a = aggr + (size_t)n * 256;
    a[lane]       = mean;
    a[64 + lane]  = mn;
    a[128 + lane] = mx;
    a[192 + lane] = sd;
}

// ---------------------------------------------------------------------------
// out = x@Wx^T + aggr@Wa^T + amp*(aggr@Wb^T) + att*(aggr@Wc^T) + post_b
// x_next = relu(out @ lin_w^T + lin_b)     -- fused, 64 rows/block
__global__ __launch_bounds__(256) void k_post(const float* __restrict__ x,
                                              const float* __restrict__ aggr,
                                              const float* __restrict__ ampv,
                                              const float* __restrict__ attv,
                                              const float* __restrict__ post_w,
                                              const float* __restrict__ post_b,
                                              const float* __restrict__ lin_w,
                                              const float* __restrict__ lin_b,
                                              float* __restrict__ xout) {
    __shared__ float At[64][68];   // A^T chunk: At[kk][r]
    __shared__ float Wt[64][68];   // W^T chunk: Wt[kk][c]
    __shared__ float ampS[64], attS[64];
    int t = threadIdx.x;
    int c4 = (t & 15) * 4;
    int r4 = (t >> 4) * 4;
    int rowBase = blockIdx.x * 64;

    if (t < 64) {
        int row = rowBase + t;
        ampS[t] = (row < N_NODES) ? ampv[row] : 0.f;
    } else if (t < 128) {
        int r = t - 64, row = rowBase + r;
        attS[r] = (row < N_NODES) ? attv[row] : 0.f;
    }

    float acc[4][4] = {{0}};
    for (int ch = 0; ch < 13; ++ch) {
        __syncthreads();
        for (int idx = t; idx < 4096; idx += 256) {
            int cc = idx >> 6, kk = idx & 63;
            Wt[kk][cc] = post_w[cc * 832 + ch * 64 + kk];
        }
        for (int idx = t; idx < 4096; idx += 256) {
            int r = idx >> 6, kk = idx & 63;
            int row = rowBase + r;
            float v = 0.f;
            if (row < N_NODES) {
                if (ch == 0) {
                    v = x[row * 64 + kk];
                } else {
                    int sub = (ch - 1) & 3;
                    float a = aggr[(size_t)row * 256 + sub * 64 + kk];
                    float s = (ch <= 4) ? 1.f : ((ch <= 8) ? ampS[r] : attS[r]);
                    v = a * s;
                }
            }
            At[kk][r] = v;
        }
        __syncthreads();
        #pragma unroll 4
        for (int kk = 0; kk < 64; ++kk) {
            float4 a = *(const float4*)&At[kk][r4];
            float4 w = *(const float4*)&Wt[kk][c4];
            float av[4] = {a.x, a.y, a.z, a.w};
            float wv[4] = {w.x, w.y, w.z, w.w};
            #pragma unroll
            for (int i = 0; i < 4; ++i)
                #pragma unroll
                for (int j = 0; j < 4; ++j)
                    acc[i][j] += av[i] * wv[j];
        }
    }

    float pb[4];
    #pragma unroll
    for (int j = 0; j < 4; ++j) pb[j] = post_b[c4 + j];

    __syncthreads();   // everyone done reading At/Wt of last chunk
    // write out^T into At: At[c][r] = out[r][c]; stage lin weights into Wt
    #pragma unroll
    for (int j = 0; j < 4; ++j) {
        float4 v = make_float4(acc[0][j] + pb[j], acc[1][j] + pb[j],
                               acc[2][j] + pb[j], acc[3][j] + pb[j]);
        *(float4*)&At[c4 + j][r4] = v;
    }
    for (int idx = t; idx < 4096; idx += 256) {
        int cc = idx >> 6, kk = idx & 63;
        Wt[kk][cc] = lin_w[cc * 64 + kk];
    }
    __syncthreads();

    float lb[4];
    #pragma unroll
    for (int j = 0; j < 4; ++j) lb[j] = lin_b[c4 + j];
    float acc2[4][4];
    #pragma unroll
    for (int i = 0; i < 4; ++i)
        #pragma unroll
        for (int j = 0; j < 4; ++j) acc2[i][j] = lb[j];

    #pragma unroll 4
    for (int kk = 0; kk < 64; ++kk) {
        float4 a = *(const float4*)&At[kk][r4];
        float4 w = *(const float4*)&Wt[kk][c4];
        float av[4] = {a.x, a.y, a.z, a.w};
        float wv[4] = {w.x, w.y, w.z, w.w};
        #pragma unroll
        for (int i = 0; i < 4; ++i)
            #pragma unroll
            for (int j = 0; j < 4; ++j)
                acc2[i][j] += av[i] * wv[j];
    }
    #pragma unroll
    for (int i = 0; i < 4; ++i) {
        int row = rowBase + r4 + i;
        if (row < N_NODES) {
            float4 v = make_float4(fmaxf(acc2[i][0], 0.f), fmaxf(acc2[i][1], 0.f),
                                   fmaxf(acc2[i][2], 0.f), fmaxf(acc2[i][3], 0.f));
            *(float4*)&xout[row * 64 + c4] = v;
        }
    }
}

// ---------------------------------------------------------------------------
// Mean pooling: wave per 128-node slab (batch sorted -> few flushes)
__global__ __launch_bounds__(256) void k_pool(const float* __restrict__ x,
                                              const int* __restrict__ batch,
                                              float* __restrict__ g_sum,
                                              int* __restrict__ g_cnt) {
    int lane = threadIdx.x & 63;
    int wave = blockIdx.x * 4 + (threadIdx.x >> 6);
    const int NPW = 128;
    int beg = wave * NPW;
    if (beg >= N_NODES) return;
    int end = min(beg + NPW, N_NODES);
    float acc = 0.f;
    int cur = batch[beg];
    int c = 0;
    for (int n = beg; n < end; ++n) {
        int b = batch[n];
        if (b != cur) {
            atomicAdd(&g_sum[cur * 64 + lane], acc);
            if (lane == 0) atomicAdd(&g_cnt[cur], c);
            acc = 0.f; c = 0; cur = b;
        }
        acc += x[n * 64 + lane];
        ++c;
    }
    atomicAdd(&g_sum[cur * 64 + lane], acc);
    if (lane == 0) atomicAdd(&g_cnt[cur], c);
}

// Final MLP head: tiny, single block
__global__ __launch_bounds__(256) void k_mlp(const float* __restrict__ g_sum,
                                             const int* __restrict__ g_cnt,
                                             const float* __restrict__ w1,
                                             const float* __restrict__ b1,
                                             const float* __restrict__ w2,
                                             const float* __restrict__ b2,
                                             float* __restrict__ out) {
    __shared__ float g[64][64];
    __shared__ float h[64][64];
    int t = threadIdx.x;
    for (int idx = t; idx < 4096; idx += 256) {
        int gi = idx >> 6, c = idx & 63;
        float cntf = fmaxf((float)g_cnt[gi], 1.f);
        g[gi][c] = g_sum[idx] / cntf;
    }
    __syncthreads();
    for (int idx = t; idx < 4096; idx += 256) {
        int gi = idx >> 6, c = idx & 63;
        float acc = b1[c];
        for (int k = 0; k < 64; ++k) acc += g[gi][k] * w1[c * 64 + k];
        h[gi][c] = fmaxf(acc, 0.f);
    }
    __syncthreads();
    for (int idx = t; idx < 64 * NCLASSES; idx += 256) {
        int gi = idx >> 4, c = idx & 15;
        float acc = b2[c];
        for (int k = 0; k < 64; ++k) acc += h[gi][k] * w2[c * 64 + k];
        out[gi * NCLASSES + c] = acc;
    }
}

// ---------------------------------------------------------------------------
extern "C" void kernel_launch(void* const* d_in, const int* in_sizes, int n_in,
                              void* d_out, int out_size, void* d_ws, size_t ws_size,
                              hipStream_t stream) {
    const float* x      = (const float*)d_in[0];
    const int*   ei     = (const int*)d_in[1];
    const int*   batch  = (const int*)d_in[2];
    const float* pre_w  = (const float*)d_in[3];
    const float* pre_b  = (const float*)d_in[4];
    const float* post_w = (const float*)d_in[5];
    const float* post_b = (const float*)d_in[6];
    const float* lin_w  = (const float*)d_in[7];
    const float* lin_b  = (const float*)d_in[8];
    const float* mlp_w1 = (const float*)d_in[9];
    const float* mlp_b1 = (const float*)d_in[10];
    const float* mlp_w2 = (const float*)d_in[11];
    const float* mlp_b2 = (const float*)d_in[12];

    const int* src = ei;            // edge_index[0]
    const int* dst = ei + N_EDGES;  // edge_index[1]

    char* base = (char*)d_ws;
    size_t off = 0;
    auto alloc = [&](size_t bytes) -> void* {
        void* ptr = base + off;
        off += (bytes + 255) & ~(size_t)255;
        return ptr;
    };
    int*   cnt       = (int*)alloc(N_NODES * 4);
    int*   row_start = (int*)alloc((N_NODES + 1) * 4);
    int*   cursor    = (int*)alloc(N_NODES * 4);
    int*   csr_src   = (int*)alloc(N_EDGES * 4);
    int*   bsum      = (int*)alloc(64 * 4);
    int*   boff      = (int*)alloc(64 * 4);
    float* logsum    = (float*)alloc(16);
    float* inv_deg   = (float*)alloc(N_NODES * 4);
    float* ampv      = (float*)alloc(N_NODES * 4);
    float* attv      = (float*)alloc(N_NODES * 4);
    float* p         = (float*)alloc((size_t)N_NODES * 64 * 4);
    float* q         = (float*)alloc((size_t)N_NODES * 64 * 4);
    float* aggr      = (float*)alloc((size_t)N_NODES * 256 * 4);
    float* xb0       = (float*)alloc((size_t)N_NODES * 64 * 4);
    float* xb1       = (float*)alloc((size_t)N_NODES * 64 * 4);
    float* g_sum     = (float*)alloc(64 * 64 * 4);
    int*   g_cnt     = (int*)alloc(64 * 4);

    hipMemsetAsync(cnt, 0, N_NODES * 4, stream);
    hipMemsetAsync(logsum, 0, 16, stream);
    hipMemsetAsync(g_sum, 0, 64 * 64 * 4, stream);
    hipMemsetAsync(g_cnt, 0, 64 * 4, stream);

    k_count<<<(N_EDGES + 255) / 256, 256, 0, stream>>>(dst, cnt);
    k_chunk_sums<<<NCHUNKS, 256, 0, stream>>>(cnt, bsum, logsum);
    k_scan_top<<<1, 64, 0, stream>>>(bsum, boff, row_start);
    k_scan_chunks<<<NCHUNKS, 256, 0, stream>>>(cnt, boff, row_start, cursor);
    k_scatter<<<(N_EDGES + 255) / 256, 256, 0, stream>>>(src, dst, cursor, csr_src);
    k_scal<<<(N_NODES + 255) / 256, 256, 0, stream>>>(cnt, logsum, inv_deg, ampv, attv);

    const int GEMM_BLOCKS = (N_NODES + 63) / 64;   // 782
    const float* xin = x;
    float* bufs[3] = {xb0, xb1, xb0};
    for (int l = 0; l < NLAYERS; ++l) {
        k_pre<<<GEMM_BLOCKS, 256, 0, stream>>>(xin, pre_w + (size_t)l * 64 * 128,
                                               pre_b + l * 64, p, q);
        k_aggr<<<(N_NODES + 3) / 4, 256, 0, stream>>>(p, q, row_start, csr_src,
                                                      inv_deg, aggr);
        float* xo = bufs[l];
        k_post<<<GEMM_BLOCKS, 256, 0, stream>>>(xin, aggr, ampv, attv,
                                                post_w + (size_t)l * 64 * 832,
                                                post_b + l * 64,
                                                lin_w + (size_t)l * 64 * 64,
                                                lin_b + l * 64, xo);
        xin = xo;
    }

    int pool_waves = (N_NODES + 127) / 128;
    k_pool<<<(pool_waves + 3) / 4, 256, 0, stream>>>(xin, batch, g_sum, g_cnt);
    k_mlp<<<1, 256, 0, stream>>>(g_sum, g_cnt, mlp_w1, mlp_b1, mlp_w2, mlp_b2,
                                 (float*)d_out);
}

// Round 2
// 773.851 us; speedup vs baseline: 1.1776x; 1.1776x over previous
//
#include <hip/hip_runtime.h>
#include <math.h>

#define N_NODES   50000
#define N_EDGES   800000
#define NUM_GRAPHS 64
#define FDIM      64
#define HDIM      64
#define NLAYERS   3
#define NCLASSES  16
#define EPS       1e-5f

#define SCAN_CHUNK 1024
#define NCHUNKS ((N_NODES + SCAN_CHUNK - 1) / SCAN_CHUNK)   // 49

// ---------------------------------------------------------------------------
// CSR build: degree histogram
__global__ void k_count(const int* __restrict__ dst, int* __restrict__ cnt) {
    int e = blockIdx.x * 256 + threadIdx.x;
    if (e < N_EDGES) atomicAdd(&cnt[dst[e]], 1);
}

__global__ void k_chunk_sums(const int* __restrict__ cnt, int* __restrict__ bsum,
                             float* __restrict__ logsum) {
    __shared__ int   ired[256];
    __shared__ float lred[256];
    int b = blockIdx.x, t = threadIdx.x;
    int base = b * SCAN_CHUNK;
    int s = 0; float ls = 0.f;
    for (int i = t; i < SCAN_CHUNK; i += 256) {
        int idx = base + i;
        if (idx < N_NODES) {
            int v = cnt[idx];
            s += v;
            ls += logf((float)v + 1.0f);
        }
    }
    ired[t] = s; lred[t] = ls;
    __syncthreads();
    for (int off = 128; off > 0; off >>= 1) {
        if (t < off) { ired[t] += ired[t + off]; lred[t] += lred[t + off]; }
        __syncthreads();
    }
    if (t == 0) { bsum[b] = ired[0]; atomicAdd(logsum, lred[0]); }
}

__global__ void k_scan_top(const int* __restrict__ bsum, int* __restrict__ boff,
                           int* __restrict__ row_start) {
    if (threadIdx.x == 0) {
        int acc = 0;
        for (int i = 0; i < NCHUNKS; ++i) { boff[i] = acc; acc += bsum[i]; }
        row_start[N_NODES] = acc;
    }
}

__global__ void k_scan_chunks(const int* __restrict__ cnt, const int* __restrict__ boff,
                              int* __restrict__ row_start, int* __restrict__ cursor) {
    __shared__ int tsum[256];
    int b = blockIdx.x, t = threadIdx.x;
    int base = b * SCAN_CHUNK + t * 4;
    int v[4]; int s = 0;
    #pragma unroll
    for (int i = 0; i < 4; ++i) {
        int idx = base + i;
        v[i] = (idx < N_NODES) ? cnt[idx] : 0;
        s += v[i];
    }
    tsum[t] = s;
    __syncthreads();
    for (int off = 1; off < 256; off <<= 1) {
        int val = (t >= off) ? tsum[t - off] : 0;
        __syncthreads();
        tsum[t] += val;
        __syncthreads();
    }
    int excl = boff[b] + tsum[t] - s;
    #pragma unroll
    for (int i = 0; i < 4; ++i) {
        int idx = base + i;
        if (idx < N_NODES) { row_start[idx] = excl; cursor[idx] = excl; }
        excl += v[i];
    }
}

__global__ void k_scatter(const int* __restrict__ src, const int* __restrict__ dst,
                          int* __restrict__ cursor, int* __restrict__ csr_src) {
    int e = blockIdx.x * 256 + threadIdx.x;
    if (e < N_EDGES) {
        int d = dst[e];
        int slot = atomicAdd(&cursor[d], 1);
        csr_src[slot] = src[e];
    }
}

__global__ void k_scal(const int* __restrict__ cnt, const float* __restrict__ logsum,
                       float* __restrict__ inv_deg, float* __restrict__ ampv,
                       float* __restrict__ attv) {
    int n = blockIdx.x * 256 + threadIdx.x;
    if (n < N_NODES) {
        float avg = logsum[0] / (float)N_NODES;
        float degf = fmaxf((float)cnt[n], 1.0f);
        inv_deg[n] = 1.0f / degf;
        float ld = logf(degf + 1.0f);
        ampv[n] = ld / avg;
        attv[n] = avg / ld;
    }
}

// ---------------------------------------------------------------------------
// Weight folding: Wk[l][k][c] = sum_j lin_w[l][c][j] * post_w[l][j][k]
// (i.e. (Lw @ Pw) stored K-major so k_post stages it with contiguous copies)
__global__ __launch_bounds__(256) void k_comb(const float* __restrict__ post_w,
                                              const float* __restrict__ lin_w,
                                              float* __restrict__ Wk) {
    int t = threadIdx.x;
    int c  = t & 63;
    int kl = t >> 6;                       // 0..3
    int l  = blockIdx.x / 208;             // layer
    int k  = (blockIdx.x % 208) * 4 + kl;  // 0..831
    const float* lw = lin_w + (size_t)l * 4096 + c * 64;      // row c of Lw
    const float* pw = post_w + (size_t)l * 53248 + k;         // col k of Pw
    float acc = 0.f;
    #pragma unroll 8
    for (int j = 0; j < 64; ++j)
        acc += lw[j] * pw[(size_t)j * 832];
    Wk[(size_t)l * 53248 + (size_t)k * 64 + c] = acc;
}

// bc[l][c] = lin_b[l][c] + sum_j lin_w[l][c][j] * post_b[l][j]
__global__ void k_bc(const float* __restrict__ post_b, const float* __restrict__ lin_b,
                     const float* __restrict__ lin_w, float* __restrict__ bcv) {
    int t = threadIdx.x;
    if (t < 192) {
        int l = t >> 6, c = t & 63;
        float acc = lin_b[l * 64 + c];
        for (int j = 0; j < 64; ++j)
            acc += lin_w[(size_t)l * 4096 + c * 64 + j] * post_b[l * 64 + j];
        bcv[l * 64 + c] = acc;
    }
}

// ---------------------------------------------------------------------------
// p = x @ Wi^T + pre_b ; q = x @ Wj^T
__global__ __launch_bounds__(256) void k_pre(const float* __restrict__ x,
                                             const float* __restrict__ pre_w,
                                             const float* __restrict__ pre_b,
                                             float* __restrict__ p,
                                             float* __restrict__ q) {
    __shared__ float At[64][68];
    __shared__ float Wt[128][68];
    int t = threadIdx.x;
    int c4 = (t & 15) * 4;
    int r4 = (t >> 4) * 4;
    int rowBase = blockIdx.x * 64;

    for (int idx = t; idx < 64 * 128; idx += 256) {
        int cc = idx >> 7, k = idx & 127;
        Wt[k][cc] = pre_w[idx];
    }
    for (int idx = t; idx < 4096; idx += 256) {
        int r = idx >> 6, kk = idx & 63;
        int row = rowBase + r;
        At[kk][r] = (row < N_NODES) ? x[row * 64 + kk] : 0.f;
    }
    __syncthreads();

    float accp[4][4] = {{0}}, accq[4][4] = {{0}};
    #pragma unroll 4
    for (int kk = 0; kk < 64; ++kk) {
        float4 a  = *(const float4*)&At[kk][r4];
        float4 wp = *(const float4*)&Wt[kk][c4];
        float4 wq = *(const float4*)&Wt[64 + kk][c4];
        float av[4]  = {a.x, a.y, a.z, a.w};
        float wpv[4] = {wp.x, wp.y, wp.z, wp.w};
        float wqv[4] = {wq.x, wq.y, wq.z, wq.w};
        #pragma unroll
        for (int i = 0; i < 4; ++i)
            #pragma unroll
            for (int j = 0; j < 4; ++j) {
                accp[i][j] += av[i] * wpv[j];
                accq[i][j] += av[i] * wqv[j];
            }
    }
    float pb[4];
    #pragma unroll
    for (int j = 0; j < 4; ++j) pb[j] = pre_b[c4 + j];
    #pragma unroll
    for (int i = 0; i < 4; ++i) {
        int row = rowBase + r4 + i;
        if (row < N_NODES) {
            float4 vp = make_float4(accp[i][0] + pb[0], accp[i][1] + pb[1],
                                    accp[i][2] + pb[2], accp[i][3] + pb[3]);
            float4 vq = make_float4(accq[i][0], accq[i][1], accq[i][2], accq[i][3]);
            *(float4*)&p[row * 64 + c4] = vp;
            *(float4*)&q[row * 64 + c4] = vq;
        }
    }
}

// ---------------------------------------------------------------------------
// Aggregation: one wave per node, lane = channel. m_e = p[n] + q[src_e].
__global__ __launch_bounds__(256) void k_aggr(const float* __restrict__ p,
                                              const float* __restrict__ q,
                                              const int* __restrict__ row_start,
                                              const int* __restrict__ csr_src,
                                              const float* __restrict__ inv_deg,
                                              float* __restrict__ aggr) {
    int wid  = (blockIdx.x * 256 + threadIdx.x) >> 6;
    int lane = threadIdx.x & 63;
    if (wid >= N_NODES) return;
    int n = wid;
    float pv = p[n * 64 + lane];
    int beg = row_start[n], end = row_start[n + 1];
    float sum = 0.f, sq = 0.f;
    float mn = INFINITY, mx = -INFINITY;
    int e = beg;
    for (; e + 1 < end; e += 2) {
        int s0 = csr_src[e];
        int s1 = csr_src[e + 1];
        float m0 = pv + q[s0 * 64 + lane];
        float m1 = pv + q[s1 * 64 + lane];
        sum += m0; sq += m0 * m0; mn = fminf(mn, m0); mx = fmaxf(mx, m0);
        sum += m1; sq += m1 * m1; mn = fminf(mn, m1); mx = fmaxf(mx, m1);
    }
    if (e < end) {
        int s0 = csr_src[e];
        float m0 = pv + q[s0 * 64 + lane];
        sum += m0; sq += m0 * m0; mn = fminf(mn, m0); mx = fmaxf(mx, m0);
    }
    float id = inv_deg[n];
    float mean = sum * id;
    float var  = fmaxf(sq * id - mean * mean, 0.f);
    float sd   = sqrtf(var + EPS);
    if (end <= beg) { mn = 0.f; mx = 0.f; }
    float* a = aggr + (size_t)n * 256;
    a[lane]       = mean;
    a[64 + lane]  = mn;
    a[128 + lane] = mx;
    a[192 + lane] = sd;
}

// ---------------------------------------------------------------------------
// x_next = relu( A @ Wk + bc ),  A = [x | aggr | amp*aggr | att*aggr]  [N,832]
// Block: 64 rows x 64 cols, 4 waves; wave w accumulates K in [208w, 208w+208),
// 13 chunks of 16 kk, private LDS staging (no barriers in K-loop),
// 8x8 register tile per thread, then a serialized in-LDS combine.
__global__ __launch_bounds__(256) void k_post(const float* __restrict__ x,
                                              const float* __restrict__ aggr,
                                              const float* __restrict__ ampv,
                                              const float* __restrict__ attv,
                                              const float* __restrict__ Wk,
                                              const float* __restrict__ bc,
                                              float* __restrict__ xout) {
    __shared__ float smem[8448];   // 4x[16][68] At + 4x[16][64] Wt; combine overlay
    int t = threadIdx.x;
    int w = t >> 6;
    int l = t & 63;
    float* At = smem + w * (16 * 68);
    float* Wt = smem + 4 * (16 * 68) + w * (16 * 64);
    int rowBase = blockIdx.x * 64;

    int r8 = (l >> 3) * 8;   // 8 row-groups
    int c8 = (l & 7) * 8;    // 8 col-groups
    int srow = l >> 2;       // staging: 16 rows per pass
    int skq  = l & 3;        // staging: k-quad

    float acc[8][8];
    #pragma unroll
    for (int i = 0; i < 8; ++i)
        #pragma unroll
        for (int j = 0; j < 8; ++j) acc[i][j] = 0.f;

    int kk0 = w * 208;
    for (int ch = 0; ch < 13; ++ch, kk0 += 16) {
        // stage A-tile (transposed): At[kk][row], pad 68 -> 2-way (free) writes
        #pragma unroll
        for (int ps = 0; ps < 4; ++ps) {
            int row  = srow + ps * 16;
            int grow = rowBase + row;
            int kk   = kk0 + skq * 4;
            float4 v = make_float4(0.f, 0.f, 0.f, 0.f);
            if (grow < N_NODES) {
                if (kk < 64) {
                    v = *(const float4*)&x[(size_t)grow * 64 + kk];
                } else if (kk < 320) {
                    v = *(const float4*)&aggr[(size_t)grow * 256 + (kk - 64)];
                } else if (kk < 576) {
                    v = *(const float4*)&aggr[(size_t)grow * 256 + (kk - 320)];
                    float s = ampv[grow];
                    v.x *= s; v.y *= s; v.z *= s; v.w *= s;
                } else {
                    v = *(const float4*)&aggr[(size_t)grow * 256 + (kk - 576)];
                    float s = attv[grow];
                    v.x *= s; v.y *= s; v.z *= s; v.w *= s;
                }
            }
            At[(skq * 4 + 0) * 68 + row] = v.x;
            At[(skq * 4 + 1) * 68 + row] = v.y;
            At[(skq * 4 + 2) * 68 + row] = v.z;
            At[(skq * 4 + 3) * 68 + row] = v.w;
        }
        // stage W-tile: contiguous copy (Wk is K-major)
        {
            const float4* wsrc = (const float4*)(Wk + (size_t)kk0 * 64);
            float4* wdst = (float4*)Wt;
            #pragma unroll
            for (int ps = 0; ps < 4; ++ps)
                wdst[l + ps * 64] = wsrc[l + ps * 64];
        }
        asm volatile("s_waitcnt lgkmcnt(0)" ::: "memory");
        // compute 16 kk, 8x8 per thread
        #pragma unroll
        for (int kk = 0; kk < 16; ++kk) {
            float4 a0 = *(const float4*)&At[kk * 68 + r8];
            float4 a1 = *(const float4*)&At[kk * 68 + r8 + 4];
            float4 w0 = *(const float4*)&Wt[kk * 64 + c8];
            float4 w1 = *(const float4*)&Wt[kk * 64 + c8 + 4];
            float av[8] = {a0.x, a0.y, a0.z, a0.w, a1.x, a1.y, a1.z, a1.w};
            float wv[8] = {w0.x, w0.y, w0.z, w0.w, w1.x, w1.y, w1.z, w1.w};
            #pragma unroll
            for (int i = 0; i < 8; ++i)
                #pragma unroll
                for (int j = 0; j < 8; ++j)
                    acc[i][j] += av[i] * wv[j];
        }
    }

    // combine the 4 waves' partial sums; lane-major stride-65 layout is
    // conflict-free (bank = (l + m) % 32)
    float* cbuf = smem;
    #pragma unroll
    for (int s = 1; s < 4; ++s) {
        __syncthreads();
        if (w == s) {
            #pragma unroll
            for (int i = 0; i < 8; ++i)
                #pragma unroll
                for (int j = 0; j < 8; ++j)
                    cbuf[l * 65 + i * 8 + j] = acc[i][j];
        }
        __syncthreads();
        if (w == 0) {
            #pragma unroll
            for (int i = 0; i < 8; ++i)
                #pragma unroll
                for (int j = 0; j < 8; ++j)
                    acc[i][j] += cbuf[l * 65 + i * 8 + j];
        }
    }
    if (w == 0) {
        float bias[8];
        #pragma unroll
        for (int j = 0; j < 8; ++j) bias[j] = bc[c8 + j];
        #pragma unroll
        for (int i = 0; i < 8; ++i) {
            int grow = rowBase + r8 + i;
            if (grow < N_NODES) {
                float4 o0 = make_float4(fmaxf(acc[i][0] + bias[0], 0.f),
                                        fmaxf(acc[i][1] + bias[1], 0.f),
                                        fmaxf(acc[i][2] + bias[2], 0.f),
                                        fmaxf(acc[i][3] + bias[3], 0.f));
                float4 o1 = make_float4(fmaxf(acc[i][4] + bias[4], 0.f),
                                        fmaxf(acc[i][5] + bias[5], 0.f),
                                        fmaxf(acc[i][6] + bias[6], 0.f),
                                        fmaxf(acc[i][7] + bias[7], 0.f));
                *(float4*)&xout[(size_t)grow * 64 + c8]     = o0;
                *(float4*)&xout[(size_t)grow * 64 + c8 + 4] = o1;
            }
        }
    }
}

// ---------------------------------------------------------------------------
__global__ __launch_bounds__(256) void k_pool(const float* __restrict__ x,
                                              const int* __restrict__ batch,
                                              float* __restrict__ g_sum,
                                              int* __restrict__ g_cnt) {
    int lane = threadIdx.x & 63;
    int wave = blockIdx.x * 4 + (threadIdx.x >> 6);
    const int NPW = 128;
    int beg = wave * NPW;
    if (beg >= N_NODES) return;
    int end = min(beg + NPW, N_NODES);
    float acc = 0.f;
    int cur = batch[beg];
    int c = 0;
    for (int n = beg; n < end; ++n) {
        int b = batch[n];
        if (b != cur) {
            atomicAdd(&g_sum[cur * 64 + lane], acc);
            if (lane == 0) atomicAdd(&g_cnt[cur], c);
            acc = 0.f; c = 0; cur = b;
        }
        acc += x[n * 64 + lane];
        ++c;
    }
    atomicAdd(&g_sum[cur * 64 + lane], acc);
    if (lane == 0) atomicAdd(&g_cnt[cur], c);
}

__global__ __launch_bounds__(256) void k_mlp(const float* __restrict__ g_sum,
                                             const int* __restrict__ g_cnt,
                                             const float* __restrict__ w1,
                                             const float* __restrict__ b1,
                                             const float* __restrict__ w2,
                                             const float* __restrict__ b2,
                                             float* __restrict__ out) {
    __shared__ float g[64][64];
    __shared__ float h[64][64];
    int t = threadIdx.x;
    for (int idx = t; idx < 4096; idx += 256) {
        int gi = idx >> 6, c = idx & 63;
        float cntf = fmaxf((float)g_cnt[gi], 1.f);
        g[gi][c] = g_sum[idx] / cntf;
    }
    __syncthreads();
    for (int idx = t; idx < 4096; idx += 256) {
        int gi = idx >> 6, c = idx & 63;
        float acc = b1[c];
        for (int k = 0; k < 64; ++k) acc += g[gi][k] * w1[c * 64 + k];
        h[gi][c] = fmaxf(acc, 0.f);
    }
    __syncthreads();
    for (int idx = t; idx < 64 * NCLASSES; idx += 256) {
        int gi = idx >> 4, c = idx & 15;
        float acc = b2[c];
        for (int k = 0; k < 64; ++k) acc += h[gi][k] * w2[c * 64 + k];
        out[gi * NCLASSES + c] = acc;
    }
}

// ---------------------------------------------------------------------------
extern "C" void kernel_launch(void* const* d_in, const int* in_sizes, int n_in,
                              void* d_out, int out_size, void* d_ws, size_t ws_size,
                              hipStream_t stream) {
    const float* x      = (const float*)d_in[0];
    const int*   ei     = (const int*)d_in[1];
    const int*   batch  = (const int*)d_in[2];
    const float* pre_w  = (const float*)d_in[3];
    const float* pre_b  = (const float*)d_in[4];
    const float* post_w = (const float*)d_in[5];
    const float* post_b = (const float*)d_in[6];
    const float* lin_w  = (const float*)d_in[7];
    const float* lin_b  = (const float*)d_in[8];
    const float* mlp_w1 = (const float*)d_in[9];
    const float* mlp_b1 = (const float*)d_in[10];
    const float* mlp_w2 = (const float*)d_in[11];
    const float* mlp_b2 = (const float*)d_in[12];

    const int* src = ei;
    const int* dst = ei + N_EDGES;

    char* base = (char*)d_ws;
    size_t off = 0;
    auto alloc = [&](size_t bytes) -> void* {
        void* ptr = base + off;
        off += (bytes + 255) & ~(size_t)255;
        return ptr;
    };
    int*   cnt       = (int*)alloc(N_NODES * 4);
    int*   row_start = (int*)alloc((N_NODES + 1) * 4);
    int*   cursor    = (int*)alloc(N_NODES * 4);
    int*   csr_src   = (int*)alloc(N_EDGES * 4);
    int*   bsum      = (int*)alloc(64 * 4);
    int*   boff      = (int*)alloc(64 * 4);
    float* logsum    = (float*)alloc(16);
    float* inv_deg   = (float*)alloc(N_NODES * 4);
    float* ampv      = (float*)alloc(N_NODES * 4);
    float* attv      = (float*)alloc(N_NODES * 4);
    float* p         = (float*)alloc((size_t)N_NODES * 64 * 4);
    float* q         = (float*)alloc((size_t)N_NODES * 64 * 4);
    float* aggr      = (float*)alloc((size_t)N_NODES * 256 * 4);
    float* xb0       = (float*)alloc((size_t)N_NODES * 64 * 4);
    float* xb1       = (float*)alloc((size_t)N_NODES * 64 * 4);
    float* g_sum     = (float*)alloc(64 * 64 * 4);
    int*   g_cnt     = (int*)alloc(64 * 4);
    float* Wk        = (float*)alloc((size_t)3 * 832 * 64 * 4);
    float* bcv       = (float*)alloc(3 * 64 * 4);

    hipMemsetAsync(cnt, 0, N_NODES * 4, stream);
    hipMemsetAsync(logsum, 0, 16, stream);
    hipMemsetAsync(g_sum, 0, 64 * 64 * 4, stream);
    hipMemsetAsync(g_cnt, 0, 64 * 4, stream);

    // weight folding (independent of graph work)
    k_comb<<<624, 256, 0, stream>>>(post_w, lin_w, Wk);
    k_bc<<<1, 256, 0, stream>>>(post_b, lin_b, lin_w, bcv);

    k_count<<<(N_EDGES + 255) / 256, 256, 0, stream>>>(dst, cnt);
    k_chunk_sums<<<NCHUNKS, 256, 0, stream>>>(cnt, bsum, logsum);
    k_scan_top<<<1, 64, 0, stream>>>(bsum, boff, row_start);
    k_scan_chunks<<<NCHUNKS, 256, 0, stream>>>(cnt, boff, row_start, cursor);
    k_scatter<<<(N_EDGES + 255) / 256, 256, 0, stream>>>(src, dst, cursor, csr_src);
    k_scal<<<(N_NODES + 255) / 256, 256, 0, stream>>>(cnt, logsum, inv_deg, ampv, attv);

    const int GEMM_BLOCKS = (N_NODES + 63) / 64;   // 782
    const float* xin = x;
    float* bufs[3] = {xb0, xb1, xb0};
    for (int l = 0; l < NLAYERS; ++l) {
        k_pre<<<GEMM_BLOCKS, 256, 0, stream>>>(xin, pre_w + (size_t)l * 64 * 128,
                                               pre_b + l * 64, p, q);
        k_aggr<<<(N_NODES + 3) / 4, 256, 0, stream>>>(p, q, row_start, csr_src,
                                                      inv_deg, aggr);
        float* xo = bufs[l];
        k_post<<<GEMM_BLOCKS, 256, 0, stream>>>(xin, aggr, ampv, attv,
                                                Wk + (size_t)l * 53248,
                                                bcv + l * 64, xo);
        xin = xo;
    }

    int pool_waves = (N_NODES + 127) / 128;
    k_pool<<<(pool_waves + 3) / 4, 256, 0, stream>>>(xin, batch, g_sum, g_cnt);
    k_mlp<<<1, 256, 0, stream>>>(g_sum, g_cnt, mlp_w1, mlp_b1, mlp_w2, mlp_b2,
                                 (float*)d_out);
}